// Round 3
// baseline (144.720 us; speedup 1.0000x reference)
//
#include <hip/hip_runtime.h>
#include <hip/hip_bf16.h>
#include <cstdint>

// Problem dims (fixed by reference)
#define B_  16
#define N_  32
#define L_  2048
#define D_  16
#define M_  32
#define K_  3
#define W_  2046   // (L - K)/STRIDE + 1

typedef __bf16 bf16x8 __attribute__((ext_vector_type(8)));
typedef float  f32x4  __attribute__((ext_vector_type(4)));

union frag_cast { uint4 u; bf16x8 f; };

// pack two fp32 -> one u32 holding two RTNE bf16 (a in low half)
__device__ __forceinline__ uint32_t pk2(float a, float b) {
    __hip_bfloat162 p = __float22bfloat162_rn(make_float2(a, b));
    union { __hip_bfloat162 h; uint32_t u; } cv; cv.h = p; return cv.u;
}

// ---------------------------------------------------------------------------
// Setup: transpose + scale weights into MFMA B-fragment order in d_ws.
// (ROUND-3/5 VERIFIED MAPPING — values unchanged.)
// GEMM: K index κ = (k*32 + n)*4 + x  (k-major), col c = m*4 + d.
// ws layout: uint4[ct(8)][kc(12)][lane(64)]; lane's uint4 = 8 bf16 =
// B[κ = kc*32 + (lane>>4)*8 + j][col = ct*16 + (lane&15)], j = 0..7.
// half h covers j = h*4 .. h*4+3  (n = n0 + h, x = j&3).
// ---------------------------------------------------------------------------
__global__ __launch_bounds__(64) void caps_setup(const float* __restrict__ wp,
                                                 uint2* __restrict__ ws2) {
    const int gid  = blockIdx.x * 64 + threadIdx.x;   // 0..12287
    const int i    = gid >> 1;                        // uint4 index 0..6143
    const int half = gid & 1;
    const int ct   = i / 768;
    const int rem  = i - ct * 768;
    const int kc   = rem >> 6;
    const int lane = rem & 63;
    const int q    = lane >> 4;
    const int col  = (ct << 4) | (lane & 15);
    const int m = col >> 2, d = col & 3;
    const int k = kc >> 2;
    const int n = (kc & 3) * 8 + q * 2 + half;        // n0 + (j>>2)
    float f[4];
#pragma unroll
    for (int x = 0; x < 4; ++x)
        f[x] = wp[(((k * 32 + n) * 4 + x) * 4 + d) * 32 + m] * 0.03125f;
    uint2 o;
    o.x = pk2(f[0], f[1]); o.y = pk2(f[2], f[3]);
    ws2[i * 2 + half] = o;
}

// x LDS tile layout (per slab buffer): byte addr =
//   (n>>1)*1184 + w_local*64 + (e>>2)*16 + (n&1)*8   (+ (e&3)*2 in-granule)
// 18 w rows x 32 n, bf16.  One MFMA A-frag uint4 per lane; K-loop A-load is
// ONE ds_read_b128 with compile-time immediate offset.
#define XSTRIDE_N2 1184
#define XLDS_BYTES (16 * XSTRIDE_N2)   // 18944 B per buffer

// ---------------------------------------------------------------------------
// R8 restructure: amortization (R7) + occupancy (R1) combined.
// Block = 512 thr = 8 waves; EACH WAVE OWNS ONE COL-TILE (ct = wave).
// Per-wave regs collapse: breg[12]=48 (was 96), acc[4]=16 (was 32), stage
// regs 24 (1152 pairs / 512 thr) -> ~120 VGPR, fits launch_bounds(512,4)
// (128-VGPR budget) -> 2 blocks/CU = 16 waves/CU = 4 waves/SIMD (2x R7).
// Keeps: grid (32,16), 4 slabs x 16 w per block, breg loaded ONCE per block,
// reg-prefetch of slab s+1 before slab s K-loop, one barrier per slab.
// Accepted cost: A frags read by 8 waves instead of 4 (LDS pipe ~10 us/CU,
// still under the ~17 us HBM floor).
// ---------------------------------------------------------------------------
__global__ __launch_bounds__(512, 4) void caps_mfma(
    const float* __restrict__ xp,   // [B][N][L][16]
    const uint4* __restrict__ ws,   // B frags
    const float* __restrict__ gp,   // [16]
    const float* __restrict__ bp,   // [16]
    float* __restrict__ out)        // [B][M][W][16]
{
    __shared__ __align__(16) unsigned char xs[2 * XLDS_BYTES];

    const int tid  = threadIdx.x;
    const int ct   = tid >> 6;         // wave id == col-tile id (0..7)
    const int lane = tid & 63;
    const int q    = lane >> 4;        // quad id
    const int l15  = lane & 15;
    const int dL   = lane & 3;         // d (out inner-of-4)
    const int msub = (lane >> 2) & 3;  // m within col-tile
    const int b    = blockIdx.y;
    const int W0   = blockIdx.x * 64;  // block's first w (64-w super-tile)

    const float* xb = xp + (size_t)b * N_ * L_ * D_;

    // ---- per-thread stage geometry (slab-independent); 1152 pair-granules
    // over 512 threads -> 3 iters (last: tid < 128 only) ----
    int  goff[3];    // float offset of (n-pair, f4) within xb, w excluded
    int  lbase[3];   // LDS byte offset within a buffer
    int  wA[3];      // w row 0..17
    bool val[3];
#pragma unroll
    for (int i = 0; i < 3; ++i) {
        const int idx = i * 512 + tid;          // 0..1535, valid < 1152
        val[i] = (i < 2) || (idx < 1152);
        const int f4 = idx & 3;
        const int wn = idx >> 2;                // 0..287 (mod range)
        const int w  = wn % 18;
        const int n2 = wn / 18;                 // 0..15
        wA[i]    = w;
        lbase[i] = n2 * XSTRIDE_N2 + w * 64 + f4 * 16;
        goff[i]  = (2 * n2) * L_ * D_ + f4 * 4;
    }

    float4 ra[3], rb[3];

    // issue slab-s stage loads into registers (pair granule: n even + n odd)
    auto issue = [&](int s) {
#pragma unroll
        for (int i = 0; i < 3; ++i) if (val[i]) {
            int gw = W0 + s * 16 + wA[i];
            if (gw > L_ - 1) gw = L_ - 1;       // clamp halo
            const float* p0 = xb + goff[i] + (size_t)gw * D_;
            ra[i] = *reinterpret_cast<const float4*>(p0);                    // n even
            rb[i] = *reinterpret_cast<const float4*>(p0 + (size_t)L_ * D_);  // n odd
        }
    };
    // convert + write one full uint4 per lane (conflict-free ds_write_b128)
    auto wrlds = [&](int bufoff) {
#pragma unroll
        for (int i = 0; i < 3; ++i) if (val[i]) {
            uint4 o;
            o.x = pk2(ra[i].x, ra[i].y); o.y = pk2(ra[i].z, ra[i].w);  // n even
            o.z = pk2(rb[i].x, rb[i].y); o.w = pk2(rb[i].z, rb[i].w);  // n odd
            *reinterpret_cast<uint4*>(&xs[bufoff + lbase[i]]) = o;
        }
    };

    // ---- prologue: slab-0 loads + persistent B frags + gamma/beta ----
    issue(0);

    uint4 breg[12];                             // 48 VGPR, whole block life
#pragma unroll
    for (int kc = 0; kc < 12; ++kc)
        breg[kc] = ws[ct * 768 + kc * 64 + lane];

    float gmv[4], btv[4];
#pragma unroll
    for (int r = 0; r < 4; ++r) { gmv[r] = gp[r * 4 + dL]; btv[r] = bp[r * 4 + dL]; }

    wrlds(0);
    __syncthreads();

    // Lane-dependent A base; buffer/kc/rt offsets are compile-time immediates.
    const unsigned char* ap =
        &xs[q * XSTRIDE_N2 + (l15 >> 2) * 64 + (l15 & 3) * 16];

#pragma unroll
    for (int s = 0; s < 4; ++s) {
        const int cur = (s & 1) * XLDS_BYTES;

        if (s < 3) {
            issue(s + 1);                       // prefetch next slab -> regs
            __builtin_amdgcn_sched_barrier(0);  // pin issue point (no sinking)
        }

        f32x4 acc[4];
#pragma unroll
        for (int rt = 0; rt < 4; ++rt)
            acc[rt] = (f32x4){0.f, 0.f, 0.f, 0.f};

        // ---- K-loop: pure LDS + MFMA, breg resident, no barriers ----
#pragma unroll
        for (int kc = 0; kc < 12; ++kc) {
            const int k  = kc >> 2;             // tap
            const int kn = kc & 3;              // n-chunk
            frag_cast bc; bc.u = breg[kc];
#pragma unroll
            for (int rt = 0; rt < 4; ++rt) {
                frag_cast c;
                c.u = *reinterpret_cast<const uint4*>(
                    ap + cur + kn * 4736 + k * 64 + rt * 256);
                acc[rt] = __builtin_amdgcn_mfma_f32_16x16x32_bf16(
                    c.f, bc.f, acc[rt], 0, 0, 0);
            }
        }

        // ---- fused LayerNorm + store (R3/R5-VERIFIED mapping) ----
        // D layout: row = q*4 + r -> (w_sub=q, a=r); col = l15 -> (m, d=dL).
#pragma unroll
        for (int rt = 0; rt < 4; ++rt) {
            const int wv = W0 + s * 16 + rt * 4 + q;
            const f32x4 v = acc[rt];
            float ss = v[0] + v[1] + v[2] + v[3];
            float sq = v[0]*v[0] + v[1]*v[1] + v[2]*v[2] + v[3]*v[3];
            ss += __shfl_xor(ss, 1); ss += __shfl_xor(ss, 2);
            sq += __shfl_xor(sq, 1); sq += __shfl_xor(sq, 2);
            const float mu   = ss * (1.f / 16.f);
            const float var  = sq * (1.f / 16.f) - mu * mu;
            const float rstd = rsqrtf(var + 1e-5f);
            if (wv < W_) {
                const int m = ct * 4 + msub;
                float* op = out + ((size_t)(b * M_ + m) * W_ + wv) * D_ + dL;
#pragma unroll
                for (int r = 0; r < 4; ++r)
                    op[r * 4] = gmv[r] * (v[r] - mu) * rstd + btv[r];
            }
        }

        // ---- hand off next slab: write other buffer, single barrier ----
        if (s < 3) {
            wrlds(cur ^ XLDS_BYTES);
            __syncthreads();
        }
    }
}

extern "C" void kernel_launch(void* const* d_in, const int* in_sizes, int n_in,
                              void* d_out, int out_size, void* d_ws, size_t ws_size,
                              hipStream_t stream) {
    const float* x  = (const float*)d_in[0];
    const float* w  = (const float*)d_in[1];
    const float* g  = (const float*)d_in[2];
    const float* be = (const float*)d_in[3];
    float* out = (float*)d_out;

    caps_setup<<<192, 64, 0, stream>>>(w, (uint2*)d_ws);
    caps_mfma<<<dim3(32, 16), 512, 0, stream>>>(
        x, (const uint4*)d_ws, g, be, out);
}

// Round 4
// 135.087 us; speedup vs baseline: 1.0713x; 1.0713x over previous
//
#include <hip/hip_runtime.h>
#include <hip/hip_bf16.h>
#include <cstdint>

// Problem dims (fixed by reference)
#define B_  16
#define N_  32
#define L_  2048
#define D_  16
#define M_  32
#define K_  3
#define W_  2046   // (L - K)/STRIDE + 1

typedef __bf16 bf16x8 __attribute__((ext_vector_type(8)));
typedef float  f32x4  __attribute__((ext_vector_type(4)));

union frag_cast { uint4 u; bf16x8 f; };

// pack two fp32 -> one u32 holding two RTNE bf16 (a in low half)
__device__ __forceinline__ uint32_t pk2(float a, float b) {
    __hip_bfloat162 p = __float22bfloat162_rn(make_float2(a, b));
    union { __hip_bfloat162 h; uint32_t u; } cv; cv.h = p; return cv.u;
}

// ---------------------------------------------------------------------------
// Setup: transpose + scale weights into MFMA B-fragment order in d_ws.
// (ROUND-3/5 VERIFIED MAPPING — values unchanged.)
// GEMM: K index κ = (k*32 + n)*4 + x  (k-major), col c = m*4 + d.
// ws layout: uint4[ct(8)][kc(12)][lane(64)]; lane's uint4 = 8 bf16 =
// B[κ = kc*32 + (lane>>4)*8 + j][col = ct*16 + (lane&15)], j = 0..7.
// half h covers j = h*4 .. h*4+3  (n = n0 + h, x = j&3).
// ---------------------------------------------------------------------------
__global__ __launch_bounds__(64) void caps_setup(const float* __restrict__ wp,
                                                 uint2* __restrict__ ws2) {
    const int gid  = blockIdx.x * 64 + threadIdx.x;   // 0..12287
    const int i    = gid >> 1;                        // uint4 index 0..6143
    const int half = gid & 1;
    const int ct   = i / 768;
    const int rem  = i - ct * 768;
    const int kc   = rem >> 6;
    const int lane = rem & 63;
    const int q    = lane >> 4;
    const int col  = (ct << 4) | (lane & 15);
    const int m = col >> 2, d = col & 3;
    const int k = kc >> 2;
    const int n = (kc & 3) * 8 + q * 2 + half;        // n0 + (j>>2)
    float f[4];
#pragma unroll
    for (int x = 0; x < 4; ++x)
        f[x] = wp[(((k * 32 + n) * 4 + x) * 4 + d) * 32 + m] * 0.03125f;
    uint2 o;
    o.x = pk2(f[0], f[1]); o.y = pk2(f[2], f[3]);
    ws2[i * 2 + half] = o;
}

// x LDS tile layout (per slab buffer): byte addr =
//   (n>>1)*1184 + w_local*64 + (e>>2)*16 + (n&1)*8   (+ (e&3)*2 in-granule)
// 18 w rows x 32 n, bf16.  One MFMA A-frag uint4 per lane; K-loop A-load is
// ONE ds_read_b128 with compile-time immediate offset.
#define XSTRIDE_N2 1184
#define XLDS_BYTES (16 * XSTRIDE_N2)   // 18944 B per buffer

// ---------------------------------------------------------------------------
// R9 = R7 structure (best measured: 44.2 us, VGPR=120, no spill) with the
// grid-limited occupancy fixed: grid (64,16) = 1024 blocks, 2 slabs x 16 w
// = 32 w per block.  VGPR=120 allows 4 waves/SIMD => 4 blocks/CU resident
// (16 waves/CU, 2x R7); LDS 4 x 37888 = 148 KiB < 160 KiB fits.
// Keeps per-wave-2-ct mapping (R8's 1-ct/8-wave variant triggered the
// compiler's 64-VGPR occupancy squeeze -> scratch spills, WRITE_SIZE +22MB).
//  - breg[2][12] persistent (96 VGPR), loaded ONCE per block
//  - slab 1 x-loads issued BEFORE slab 0 K-loop (sched_barrier-pinned)
//  - double-buffered LDS, ONE __syncthreads per slab
// ---------------------------------------------------------------------------
__global__ __launch_bounds__(256, 2) void caps_mfma(
    const float* __restrict__ xp,   // [B][N][L][16]
    const uint4* __restrict__ ws,   // B frags
    const float* __restrict__ gp,   // [16]
    const float* __restrict__ bp,   // [16]
    float* __restrict__ out)        // [B][M][W][16]
{
    __shared__ __align__(16) unsigned char xs[2 * XLDS_BYTES];

    const int tid  = threadIdx.x;
    const int wave = tid >> 6;
    const int lane = tid & 63;
    const int q    = lane >> 4;        // quad id
    const int l15  = lane & 15;
    const int dL   = lane & 3;         // d (out inner-of-4)
    const int msub = (lane >> 2) & 3;  // m within col-tile
    const int b    = blockIdx.y;
    const int W0   = blockIdx.x * 32;  // block's first w (32-w super-tile)
    const int ct0  = wave * 2;

    const float* xb = xp + (size_t)b * N_ * L_ * D_;

    // ---- per-thread stage geometry (slab-independent) ----
    int  goff[5];    // float offset of (n-pair, f4) within xb, w excluded
    int  lbase[5];   // LDS byte offset within a buffer
    int  wA[5];      // w row 0..17
    bool val[5];
#pragma unroll
    for (int i = 0; i < 5; ++i) {
        const int idx = i * 256 + tid;          // 0..1279, valid < 1152
        val[i] = (i < 4) || (idx < 1152);
        const int f4 = idx & 3;
        const int wn = idx >> 2;                // 0..287
        const int w  = wn % 18;
        const int n2 = wn / 18;                 // 0..15
        wA[i]    = w;
        lbase[i] = n2 * XSTRIDE_N2 + w * 64 + f4 * 16;
        goff[i]  = (2 * n2) * L_ * D_ + f4 * 4;
    }

    float4 ra[5], rb[5];

    // issue slab-s stage loads into registers (pair granule: n even + n odd)
    auto issue = [&](int s) {
#pragma unroll
        for (int i = 0; i < 5; ++i) if (val[i]) {
            int gw = W0 + s * 16 + wA[i];
            if (gw > L_ - 1) gw = L_ - 1;       // clamp halo
            const float* p0 = xb + goff[i] + (size_t)gw * D_;
            ra[i] = *reinterpret_cast<const float4*>(p0);                    // n even
            rb[i] = *reinterpret_cast<const float4*>(p0 + (size_t)L_ * D_);  // n odd
        }
    };
    // convert + write one full uint4 per lane (conflict-free ds_write_b128)
    auto wrlds = [&](int bufoff) {
#pragma unroll
        for (int i = 0; i < 5; ++i) if (val[i]) {
            uint4 o;
            o.x = pk2(ra[i].x, ra[i].y); o.y = pk2(ra[i].z, ra[i].w);  // n even
            o.z = pk2(rb[i].x, rb[i].y); o.w = pk2(rb[i].z, rb[i].w);  // n odd
            *reinterpret_cast<uint4*>(&xs[bufoff + lbase[i]]) = o;
        }
    };

    // ---- prologue: slab-0 loads + persistent B frags + gamma/beta ----
    issue(0);

    uint4 breg[2][12];                          // 96 VGPR, whole block life
#pragma unroll
    for (int cp = 0; cp < 2; ++cp)
#pragma unroll
        for (int kc = 0; kc < 12; ++kc)
            breg[cp][kc] = ws[(ct0 + cp) * 768 + kc * 64 + lane];

    float gmv[4], btv[4];
#pragma unroll
    for (int r = 0; r < 4; ++r) { gmv[r] = gp[r * 4 + dL]; btv[r] = bp[r * 4 + dL]; }

    wrlds(0);
    __syncthreads();

    // Lane-dependent A base; buffer/kc/rt offsets are compile-time immediates.
    const unsigned char* ap =
        &xs[q * XSTRIDE_N2 + (l15 >> 2) * 64 + (l15 & 3) * 16];

#pragma unroll
    for (int s = 0; s < 2; ++s) {
        const int cur = (s & 1) * XLDS_BYTES;

        if (s < 1) {
            issue(s + 1);                       // prefetch next slab -> regs
            __builtin_amdgcn_sched_barrier(0);  // pin issue point (no sinking)
        }

        f32x4 acc[4][2];
#pragma unroll
        for (int rt = 0; rt < 4; ++rt)
#pragma unroll
            for (int cp = 0; cp < 2; ++cp)
                acc[rt][cp] = (f32x4){0.f, 0.f, 0.f, 0.f};

        // ---- K-loop: pure LDS + MFMA, breg resident, no barriers ----
#pragma unroll
        for (int kc = 0; kc < 12; ++kc) {
            const int k  = kc >> 2;             // tap
            const int kn = kc & 3;              // n-chunk
            bf16x8 afr[4];
#pragma unroll
            for (int rt = 0; rt < 4; ++rt) {
                frag_cast c;
                c.u = *reinterpret_cast<const uint4*>(
                    ap + cur + kn * 4736 + k * 64 + rt * 256);
                afr[rt] = c.f;
            }
#pragma unroll
            for (int cp = 0; cp < 2; ++cp) {
                frag_cast bc; bc.u = breg[cp][kc];
#pragma unroll
                for (int rt = 0; rt < 4; ++rt)
                    acc[rt][cp] = __builtin_amdgcn_mfma_f32_16x16x32_bf16(
                        afr[rt], bc.f, acc[rt][cp], 0, 0, 0);
            }
        }

        // ---- fused LayerNorm + store (R3/R5-VERIFIED mapping) ----
        // D layout: row = q*4 + r -> (w_sub=q, a=r); col = l15 -> (m, d=dL).
#pragma unroll
        for (int rt = 0; rt < 4; ++rt) {
            const int wv = W0 + s * 16 + rt * 4 + q;
#pragma unroll
            for (int cp = 0; cp < 2; ++cp) {
                const f32x4 v = acc[rt][cp];
                float ss = v[0] + v[1] + v[2] + v[3];
                float sq = v[0]*v[0] + v[1]*v[1] + v[2]*v[2] + v[3]*v[3];
                ss += __shfl_xor(ss, 1); ss += __shfl_xor(ss, 2);
                sq += __shfl_xor(sq, 1); sq += __shfl_xor(sq, 2);
                const float mu   = ss * (1.f / 16.f);
                const float var  = sq * (1.f / 16.f) - mu * mu;
                const float rstd = rsqrtf(var + 1e-5f);
                if (wv < W_) {
                    const int m = (ct0 + cp) * 4 + msub;
                    float* op = out + ((size_t)(b * M_ + m) * W_ + wv) * D_ + dL;
#pragma unroll
                    for (int r = 0; r < 4; ++r)
                        op[r * 4] = gmv[r] * (v[r] - mu) * rstd + btv[r];
                }
            }
        }

        // ---- hand off next slab: write other buffer, single barrier ----
        if (s < 1) {
            wrlds(cur ^ XLDS_BYTES);
            __syncthreads();
        }
    }
}

extern "C" void kernel_launch(void* const* d_in, const int* in_sizes, int n_in,
                              void* d_out, int out_size, void* d_ws, size_t ws_size,
                              hipStream_t stream) {
    const float* x  = (const float*)d_in[0];
    const float* w  = (const float*)d_in[1];
    const float* g  = (const float*)d_in[2];
    const float* be = (const float*)d_in[3];
    float* out = (float*)d_out;

    caps_setup<<<192, 64, 0, stream>>>(w, (uint2*)d_ws);
    caps_mfma<<<dim3(64, 16), 256, 0, stream>>>(
        x, (const uint4*)d_ws, g, be, out);
}